// Round 9
// baseline (187.056 us; speedup 1.0000x reference)
//
#include <hip/hip_runtime.h>
#include <hip/hip_bf16.h>
#include <stdint.h>

#define M_DIM 8192
#define N_DIM 4096
#define K_DIM 4096

#define BM 256
#define BN 256
#define BK 64                 // bytes of K per LDS tile = one mfma_i32_16x16x64_i8 K
#define NT (K_DIM / BK)       // 64 K-tiles
#define DEPTH 4               // circular LDS pipeline depth

typedef int v4i __attribute__((ext_vector_type(4)));

#define AS1C(p) ((const __attribute__((address_space(1))) void*)(p))
#define AS3(p)  ((__attribute__((address_space(3))) void*)(p))

// ---------------------------------------------------------------------------
// Fused pack pass: int32 (int8-range) -> int8 for BOTH operands, one launch.
// ---------------------------------------------------------------------------
__device__ __forceinline__ int pack4(int a, int b, int c, int d) {
  return (a & 0xff) | ((b & 0xff) << 8) | ((c & 0xff) << 16) | (d << 24);
}

__global__ void pack_both_kernel(const int* __restrict__ x, const int* __restrict__ w,
                                 char* __restrict__ A8, char* __restrict__ B8,
                                 int nA, int nTot) {
  int idx = blockIdx.x * blockDim.x + threadIdx.x;
  int stride = gridDim.x * blockDim.x;
  for (int i = idx; i < nTot; i += stride) {
    const int4* pin;
    int4* pout;
    if (i < nA) {
      pin  = (const int4*)x + 4 * (size_t)i;
      pout = (int4*)A8 + i;
    } else {
      int j = i - nA;
      pin  = (const int4*)w + 4 * (size_t)j;
      pout = (int4*)B8 + j;
    }
    int4 v0 = pin[0];
    int4 v1 = pin[1];
    int4 v2 = pin[2];
    int4 v3 = pin[3];
    int4 o;
    o.x = pack4(v0.x, v0.y, v0.z, v0.w);
    o.y = pack4(v1.x, v1.y, v1.z, v1.w);
    o.z = pack4(v2.x, v2.y, v2.z, v2.w);
    o.w = pack4(v3.x, v3.y, v3.z, v3.w);
    *pout = o;
  }
}

// ---------------------------------------------------------------------------
// int8 GEMM: 256x256 tile, FOUR waves (2x2), per-wave 128x128 output.
// Rationale: per-wave LDS-read bytes per MFMA drop from 384 (128x64 wave)
// to 256 B/MFMA -> per CU per K-tile: LDS ~880 cyc vs MFMA 1306 cyc, so
// LDS can hide fully under MFMA.  1 wave/SIMD (acc 256 regs) -- overlap
// comes from ILP: next-tile ds_reads issue in MFMA shadow (no lgkm0 asm,
// no sched_barrier; compiler places minimal waits).
//
// Ring/wait math (8 gload_lds per thread per tile, DEPTH=4):
//   during tile u we issue STAGE(u+3); end-of-u: outstanding = {u+2, u+3}
//   (16 loads); vmcnt(8) -> u+2 landed; barrier -> all waves.  Hence
//   READ(t+1) during tile t is safe (t+1 <= (t-1)+2 landed).
//   STAGE(t+3) overwrites buf[(t-1)&3]: all reads of t-1 drained before
//   t-1's MFMAs, which precede the end-of-(t-1) barrier.  Safe.
// ---------------------------------------------------------------------------
__global__ __launch_bounds__(256, 1) void gemm_i8_kernel(
    const char* __restrict__ A8, const char* __restrict__ B8,
    const int* __restrict__ bias, const float* __restrict__ alpha_p,
    const float* __restrict__ beta_p, int* __restrict__ out) {
  __shared__ alignas(16) char lds[DEPTH][BM * BK + BN * BK];  // 4 x 32 KiB

  const int tid  = threadIdx.x;
  const int lane = tid & 63;
  const int wave = tid >> 6;

  // XCD-aware bijective swizzle: 512 blocks, 64 consecutive per XCD.
  const int orig = blockIdx.x;
  const int swz  = (orig & 7) * (512 / 8) + (orig >> 3);
  const int bm   = (swz >> 4) * BM;  // 32 row-tiles
  const int bn   = (swz & 15) * BN;  // 16 col-tiles

  // Staging: per operand tile 16 KB = 4 rounds x 256 thr x 16 B.
  // Pre-swizzled global chunk g = p ^ ((row>>1)&3) (both-sides swizzle).
  int aoff[4], boff[4], ldsoffA[4], ldsoffB[4];
#pragma unroll
  for (int i = 0; i < 4; ++i) {
    int linear = i * 4096 + tid * 16;
    int row = linear >> 6;           // 0..255
    int p   = (linear >> 4) & 3;
    int g   = p ^ ((row >> 1) & 3);
    ldsoffA[i] = i * 4096 + wave * 1024;        // wave-uniform LDS base
    ldsoffB[i] = 16384 + i * 4096 + wave * 1024;
    aoff[i] = (bm + row) * K_DIM + g * 16;
    boff[i] = (bn + row) * K_DIM + g * 16;
  }

#define STAGE_A(t)                                                                  \
  do {                                                                              \
    const char* ab_ = A8 + (t) * BK;                                                \
    char* base_ = &lds[(t) & (DEPTH - 1)][0];                                       \
    _Pragma("unroll") for (int i_ = 0; i_ < 4; ++i_)                                \
      __builtin_amdgcn_global_load_lds(AS1C(ab_ + aoff[i_]),                        \
                                       AS3(base_ + ldsoffA[i_]), 16, 0, 0);         \
  } while (0)

#define STAGE_B(t)                                                                  \
  do {                                                                              \
    const char* bb_ = B8 + (t) * BK;                                                \
    char* base_ = &lds[(t) & (DEPTH - 1)][0];                                       \
    _Pragma("unroll") for (int i_ = 0; i_ < 4; ++i_)                                \
      __builtin_amdgcn_global_load_lds(AS1C(bb_ + boff[i_]),                        \
                                       AS3(base_ + ldsoffB[i_]), 16, 0, 0);         \
  } while (0)

  v4i acc[8][8];
#pragma unroll
  for (int i = 0; i < 8; ++i)
#pragma unroll
    for (int j = 0; j < 8; ++j) acc[i][j] = (v4i){0, 0, 0, 0};

  const int wr = wave >> 1;         // 0..1 (M half: 128 rows)
  const int wc = wave & 1;          // 0..1 (N half: 128 cols)
  const int frow = lane & 15;
  const int fchunk = lane >> 4;
  // swizzle XOR depends only on frow (rows differ by multiples of 16) -> lane-const
  const int swzoff = ((fchunk ^ ((frow >> 1) & 3)) << 4);

  // Ping-pong fragment sets (static names, rule #20).
  v4i af0[8], bf0[8], af1[8], bf1[8];

#define READ_A(S, t)                                                                \
  do {                                                                              \
    const char* base_ = &lds[(t) & (DEPTH - 1)][0];                                 \
    _Pragma("unroll") for (int mi = 0; mi < 8; ++mi)                                \
      af##S[mi] = *(const v4i*)(base_ + (wr * 128 + mi * 16 + frow) * 64 + swzoff); \
  } while (0)

#define READ_B(S, t)                                                                \
  do {                                                                              \
    const char* base_ = &lds[(t) & (DEPTH - 1)][0];                                 \
    _Pragma("unroll") for (int nj = 0; nj < 8; ++nj)                                \
      bf##S[nj] = *(const v4i*)(base_ + 16384 +                                     \
                                (wc * 128 + nj * 16 + frow) * 64 + swzoff);         \
  } while (0)

#define MFMA_H1(S)                                                                  \
  do {                                                                              \
    __builtin_amdgcn_s_setprio(1);                                                  \
    _Pragma("unroll") for (int mi = 0; mi < 4; ++mi)                                \
      _Pragma("unroll") for (int nj = 0; nj < 8; ++nj)                              \
        acc[mi][nj] = __builtin_amdgcn_mfma_i32_16x16x64_i8(af##S[mi], bf##S[nj],   \
                                                            acc[mi][nj], 0, 0, 0); \
    __builtin_amdgcn_s_setprio(0);                                                  \
  } while (0)

#define MFMA_H2(S)                                                                  \
  do {                                                                              \
    __builtin_amdgcn_s_setprio(1);                                                  \
    _Pragma("unroll") for (int mi = 4; mi < 8; ++mi)                                \
      _Pragma("unroll") for (int nj = 0; nj < 8; ++nj)                              \
        acc[mi][nj] = __builtin_amdgcn_mfma_i32_16x16x64_i8(af##S[mi], bf##S[nj],   \
                                                            acc[mi][nj], 0, 0, 0); \
    __builtin_amdgcn_s_setprio(0);                                                  \
  } while (0)

// EV: 8 = vmcnt(8)+barrier, 0 = vmcnt(0)+barrier, -1 = nothing (tail).
#define TILE(t, C, N, STG, EV)                                                      \
  do {                                                                              \
    if (STG) STAGE_A((t) + 3);                                                      \
    if ((t) + 1 < NT) READ_A(N, (t) + 1);                                           \
    MFMA_H1(C);                                                                     \
    if (STG) STAGE_B((t) + 3);                                                      \
    if ((t) + 1 < NT) READ_B(N, (t) + 1);                                           \
    MFMA_H2(C);                                                                     \
    if ((EV) == 8) asm volatile("s_waitcnt vmcnt(8)" ::: "memory");                 \
    if ((EV) == 0) asm volatile("s_waitcnt vmcnt(0)" ::: "memory");                 \
    if ((EV) >= 0) __builtin_amdgcn_s_barrier();                                    \
  } while (0)

  // Prologue: stage tiles 0..2 (24 loads); vmcnt(8) -> tiles 0,1 landed.
  STAGE_A(0); STAGE_B(0);
  STAGE_A(1); STAGE_B(1);
  STAGE_A(2); STAGE_B(2);
  asm volatile("s_waitcnt vmcnt(8)" ::: "memory");
  __builtin_amdgcn_s_barrier();
  READ_A(0, 0); READ_B(0, 0);

  for (int t = 0; t < NT - 4; t += 2) {   // t = 0..58: stages 3..62
    TILE(t, 0, 1, true, 8);
    TILE(t + 1, 1, 0, true, 8);
  }
  TILE(NT - 4, 0, 1, true, 8);            // t=60: stages 63
  TILE(NT - 3, 1, 0, false, 0);           // t=61: vmcnt(0) -> 63 landed
  TILE(NT - 2, 0, 1, false, -1);          // t=62: reads 63's frags
  TILE(NT - 1, 1, 0, false, -1);          // t=63

  // Epilogue: D = rint(alpha*acc + beta*bias[n]).
  // C/D layout (16x16): col = lane&15, row = (lane>>4)*4 + reg.
  const float alpha = *alpha_p;
  const float beta  = *beta_p;
  const int col0 = bn + wc * 128 + frow;
  float bb8[8];
#pragma unroll
  for (int nj = 0; nj < 8; ++nj) bb8[nj] = beta * (float)bias[col0 + nj * 16];

  const int rbase = bm + wr * 128 + (lane >> 4) * 4;
#pragma unroll
  for (int mi = 0; mi < 8; ++mi) {
#pragma unroll
    for (int r = 0; r < 4; ++r) {
      size_t rowoff = (size_t)(rbase + mi * 16 + r) * N_DIM;
#pragma unroll
      for (int nj = 0; nj < 8; ++nj) {
        out[rowoff + col0 + nj * 16] =
            (int)rintf(fmaf(alpha, (float)acc[mi][nj][r], bb8[nj]));
      }
    }
  }
#undef STAGE_A
#undef STAGE_B
#undef READ_A
#undef READ_B
#undef MFMA_H1
#undef MFMA_H2
#undef TILE
}

// ---------------------------------------------------------------------------
// Safety fallback if ws is too small for the packed operands (slow but right).
// ---------------------------------------------------------------------------
__global__ void naive_kernel(const int* __restrict__ x, const int* __restrict__ w,
                             const int* __restrict__ bias,
                             const float* __restrict__ alpha_p,
                             const float* __restrict__ beta_p,
                             int* __restrict__ out) {
  size_t idx = (size_t)blockIdx.x * 256 + threadIdx.x;
  int m = (int)(idx / N_DIM);
  int n = (int)(idx % N_DIM);
  const int4* xr = (const int4*)(x + (size_t)m * K_DIM);
  const int4* wr = (const int4*)(w + (size_t)n * K_DIM);
  int acc = 0;
  for (int k = 0; k < K_DIM / 4; ++k) {
    int4 a = xr[k];
    int4 b = wr[k];
    acc += a.x * b.x + a.y * b.y + a.z * b.z + a.w * b.w;
  }
  out[idx] = (int)rintf(fmaf(*alpha_p, (float)acc, (*beta_p) * (float)bias[n]));
}

extern "C" void kernel_launch(void* const* d_in, const int* in_sizes, int n_in,
                              void* d_out, int out_size, void* d_ws, size_t ws_size,
                              hipStream_t stream) {
  const int*   x     = (const int*)d_in[0];
  const int*   w     = (const int*)d_in[1];
  const int*   bias  = (const int*)d_in[2];
  const float* alpha = (const float*)d_in[3];
  const float* beta  = (const float*)d_in[4];
  int* out = (int*)d_out;

  const size_t a8_bytes = (size_t)M_DIM * K_DIM;  // 32 MiB
  const size_t b8_bytes = (size_t)N_DIM * K_DIM;  // 16 MiB

  if (ws_size >= a8_bytes + b8_bytes) {
    char* A8 = (char*)d_ws;
    char* B8 = A8 + a8_bytes;
    const int nA = (int)(a8_bytes / 16);
    const int nTot = (int)((a8_bytes + b8_bytes) / 16);
    pack_both_kernel<<<2048, 256, 0, stream>>>(x, w, A8, B8, nA, nTot);
    const int nblk = (M_DIM / BM) * (N_DIM / BN);  // 32*16 = 512
    gemm_i8_kernel<<<nblk, 256, 0, stream>>>(A8, B8, bias, alpha, beta, out);
  } else {
    naive_kernel<<<(M_DIM * (size_t)N_DIM) / 256, 256, 0, stream>>>(x, w, bias, alpha, beta, out);
  }
}

// Round 10
// 184.224 us; speedup vs baseline: 1.0154x; 1.0154x over previous
//
#include <hip/hip_runtime.h>
#include <hip/hip_bf16.h>
#include <stdint.h>

#define M_DIM 8192
#define N_DIM 4096
#define K_DIM 4096

#define BM 256
#define BN 256
#define BK 64                 // bytes of K per LDS tile = one mfma_i32_16x16x64_i8 K
#define NT (K_DIM / BK)       // 64 K-tiles
#define DEPTH 4               // circular LDS pipeline depth

typedef int v4i __attribute__((ext_vector_type(4)));

#define AS1C(p) ((const __attribute__((address_space(1))) void*)(p))
#define AS3(p)  ((__attribute__((address_space(3))) void*)(p))

// ---------------------------------------------------------------------------
// Fused pack pass: int32 (int8-range) -> int8 for BOTH operands, one launch.
// ---------------------------------------------------------------------------
__device__ __forceinline__ int pack4(int a, int b, int c, int d) {
  return (a & 0xff) | ((b & 0xff) << 8) | ((c & 0xff) << 16) | (d << 24);
}

__global__ void pack_both_kernel(const int* __restrict__ x, const int* __restrict__ w,
                                 char* __restrict__ A8, char* __restrict__ B8,
                                 int nA, int nTot) {
  int idx = blockIdx.x * blockDim.x + threadIdx.x;
  int stride = gridDim.x * blockDim.x;
  for (int i = idx; i < nTot; i += stride) {
    const int4* pin;
    int4* pout;
    if (i < nA) {
      pin  = (const int4*)x + 4 * (size_t)i;
      pout = (int4*)A8 + i;
    } else {
      int j = i - nA;
      pin  = (const int4*)w + 4 * (size_t)j;
      pout = (int4*)B8 + j;
    }
    int4 v0 = pin[0];
    int4 v1 = pin[1];
    int4 v2 = pin[2];
    int4 v3 = pin[3];
    int4 o;
    o.x = pack4(v0.x, v0.y, v0.z, v0.w);
    o.y = pack4(v1.x, v1.y, v1.z, v1.w);
    o.z = pack4(v2.x, v2.y, v2.z, v2.w);
    o.w = pack4(v3.x, v3.y, v3.z, v3.w);
    *pout = o;
  }
}

// ---------------------------------------------------------------------------
// int8 GEMM: 256x256 tile, 8 waves (2Mx4N, per-wave 128x64), BK=64B,
// mfma_i32_16x16x64_i8, DEPTH=4 LDS ring, counted vmcnt, ONE barrier/tile,
// R8's cross-tile register prefetch, NOW WITH STATIC LDS ADDRESSING:
// 8 named base pointers (pA0..3 / pB0..3, one per ring buffer) computed
// once; every fragment read is base + compile-time immediate offset
// (mi*1024 / nj*1024) -> folds into ds_read_b128 offset:, eliminating
// ~570 cyc/tile/CU of per-tile address VALU (R8: VALUBusy 23%).
// K-loop unrolled by 4 so all buffer indices are literals.
//
//   TILE(u): STAGE_A(u+3); READ_HI(u)      [4 ds]; MFMA_LO(u)
//            STAGE_B(u+3); READ_LO(u+1)    [8 ds]; MFMA_HI(u)
//            s_waitcnt vmcnt(4); s_barrier
//
// Wait math (4 gloads per stage): end-of-u outstanding = {u+2, u+3} (8);
// vmcnt(4) -> u+2 landed (fixes R8's one-tile-early read).  During tile u,
// READ_HI(u) and READ_LO(u+1) both touch tiles already proven landed.
// STAGE(u+3) overwrites buf[(u-1)&3]: all waves' reads of u-1 were issued
// before their end-of-(u-1) barrier and serviced long before the new
// stage's write returns (m201 production pattern).
// ---------------------------------------------------------------------------
__global__ __launch_bounds__(512, 2) void gemm_i8_kernel(
    const char* __restrict__ A8, const char* __restrict__ B8,
    const int* __restrict__ bias, const float* __restrict__ alpha_p,
    const float* __restrict__ beta_p, int* __restrict__ out) {
  __shared__ alignas(16) char lds[DEPTH][BM * BK + BN * BK];  // 4 x 32 KiB

  const int tid  = threadIdx.x;
  const int lane = tid & 63;
  const int wave = tid >> 6;

  // XCD-aware bijective swizzle: 512 blocks, 64 consecutive per XCD.
  const int orig = blockIdx.x;
  const int swz  = (orig & 7) * (512 / 8) + (orig >> 3);
  const int bm   = (swz >> 4) * BM;  // 32 row-tiles
  const int bn   = (swz & 15) * BN;  // 16 col-tiles

  // Staging geometry: per operand tile 16 KB = 2 rounds x 512 thr x 16 B.
  // Pre-swizzled global chunk g = p ^ ((row>>1)&3) (both-sides swizzle).
  int aoff[2], boff[2], ldsoff[2];
#pragma unroll
  for (int i = 0; i < 2; ++i) {
    int linear = i * 8192 + tid * 16;
    int row = linear >> 6;           // 64 B rows
    int p   = (linear >> 4) & 3;
    int g   = p ^ ((row >> 1) & 3);
    ldsoff[i] = i * 8192 + wave * 1024;       // wave-uniform LDS base
    aoff[i] = (bm + row) * K_DIM + g * 16;
    boff[i] = (bn + row) * K_DIM + g * 16;
  }

#define STAGE_A(t, SB)                                                              \
  do {                                                                              \
    const char* ab_ = A8 + (size_t)(t) * BK;                                        \
    _Pragma("unroll") for (int i_ = 0; i_ < 2; ++i_)                                \
      __builtin_amdgcn_global_load_lds(AS1C(ab_ + aoff[i_]),                        \
                                       AS3(&lds[SB][0] + ldsoff[i_]), 16, 0, 0);    \
  } while (0)

#define STAGE_B(t, SB)                                                              \
  do {                                                                              \
    const char* bb_ = B8 + (size_t)(t) * BK;                                        \
    _Pragma("unroll") for (int i_ = 0; i_ < 2; ++i_)                                \
      __builtin_amdgcn_global_load_lds(AS1C(bb_ + boff[i_]),                        \
                                       AS3(&lds[SB][0] + 16384 + ldsoff[i_]),       \
                                       16, 0, 0);                                   \
  } while (0)

  v4i acc[8][4];
#pragma unroll
  for (int i = 0; i < 8; ++i)
#pragma unroll
    for (int j = 0; j < 4; ++j) acc[i][j] = (v4i){0, 0, 0, 0};

  const int wr = wave >> 2;         // 0..1 (M half: 128 rows)
  const int wc = wave & 3;          // 0..3 (N quarter: 64 cols)
  const int frow = lane & 15;
  const int fchunk = lane >> 4;
  // swizzle XOR depends only on frow (rows differ by multiples of 16) -> lane-const
  const int swzoff = ((fchunk ^ ((frow >> 1) & 3)) << 4);

  // Static per-buffer fragment base pointers (computed once; reads below use
  // compile-time immediate offsets that fold into ds_read offset:).
  // A row (wr*128 + r16*16 + frow) -> byte wr*8192 + r16*1024 + frow*64.
  // B row (wc*64  + nj*16  + frow) -> byte 16384 + wc*4096 + nj*1024 + frow*64.
  const int abase = wr * 8192 + frow * 64 + swzoff;
  const int bbase = 16384 + wc * 4096 + frow * 64 + swzoff;
  const char* pA0 = &lds[0][0] + abase;
  const char* pA1 = &lds[1][0] + abase;
  const char* pA2 = &lds[2][0] + abase;
  const char* pA3 = &lds[3][0] + abase;
  const char* pB0 = &lds[0][0] + bbase;
  const char* pB1 = &lds[1][0] + bbase;
  const char* pB2 = &lds[2][0] + bbase;
  const char* pB3 = &lds[3][0] + bbase;

  // Ping-pong lo-fragment sets (static names, rule #20) + shared afhi.
  v4i bf0[4], aflo0[4], bf1[4], aflo1[4], afhi[4];

#define READ_HI(RB)                                                                 \
  do {                                                                              \
    _Pragma("unroll") for (int mi = 0; mi < 4; ++mi)                                \
      afhi[mi] = *(const v4i*)(pA##RB + (mi + 4) * 1024);                           \
  } while (0)

#define READ_LO(S, RB)                                                              \
  do {                                                                              \
    _Pragma("unroll") for (int nj = 0; nj < 4; ++nj)                                \
      bf##S[nj] = *(const v4i*)(pB##RB + nj * 1024);                                \
    _Pragma("unroll") for (int mi = 0; mi < 4; ++mi)                                \
      aflo##S[mi] = *(const v4i*)(pA##RB + mi * 1024);                              \
  } while (0)

#define MFMA_LO(S)                                                                  \
  do {                                                                              \
    __builtin_amdgcn_s_setprio(1);                                                  \
    _Pragma("unroll") for (int mi = 0; mi < 4; ++mi)                                \
      _Pragma("unroll") for (int nj = 0; nj < 4; ++nj)                              \
        acc[mi][nj] = __builtin_amdgcn_mfma_i32_16x16x64_i8(aflo##S[mi], bf##S[nj], \
                                                            acc[mi][nj], 0, 0, 0); \
    __builtin_amdgcn_s_setprio(0);                                                  \
  } while (0)

#define MFMA_HI(S)                                                                  \
  do {                                                                              \
    __builtin_amdgcn_s_setprio(1);                                                  \
    _Pragma("unroll") for (int mi = 0; mi < 4; ++mi)                                \
      _Pragma("unroll") for (int nj = 0; nj < 4; ++nj)                              \
        acc[mi + 4][nj] = __builtin_amdgcn_mfma_i32_16x16x64_i8(afhi[mi], bf##S[nj],\
                                                                acc[mi + 4][nj],   \
                                                                0, 0, 0);          \
    __builtin_amdgcn_s_setprio(0);                                                  \
  } while (0)

// EV: 4 = vmcnt(4)+barrier, 0 = vmcnt(0)+barrier, -1 = nothing (tail).
// C/N: current/next frag set.  RBc = u&3 (this tile's buffer),
// RBn = (u+1)&3 (next tile's), SB = (u+3)&3 (stage target).
#define TILE(u, C, N, RBc, RBn, SB, STG, RDS, EV)                                   \
  do {                                                                              \
    if (STG) STAGE_A((u) + 3, SB);                                                  \
    READ_HI(RBc);                                                                   \
    MFMA_LO(C);                                                                     \
    if (STG) STAGE_B((u) + 3, SB);                                                  \
    if (RDS) READ_LO(N, RBn);                                                       \
    MFMA_HI(C);                                                                     \
    if ((EV) == 4) asm volatile("s_waitcnt vmcnt(4)" ::: "memory");                 \
    if ((EV) == 0) asm volatile("s_waitcnt vmcnt(0)" ::: "memory");                 \
    if ((EV) >= 0) __builtin_amdgcn_s_barrier();                                    \
  } while (0)

  // Prologue: stage tiles 0..2 (12 loads); vmcnt(4) -> tiles 0,1 landed.
  STAGE_A(0, 0); STAGE_B(0, 0);
  STAGE_A(1, 1); STAGE_B(1, 1);
  STAGE_A(2, 2); STAGE_B(2, 2);
  asm volatile("s_waitcnt vmcnt(4)" ::: "memory");
  __builtin_amdgcn_s_barrier();
  READ_LO(0, 0);

  for (int t = 0; t < NT - 4; t += 4) {   // t = 0,4,...,56: tiles 0..59
    TILE(t + 0, 0, 1, 0, 1, 3, true, true, 4);
    TILE(t + 1, 1, 0, 1, 2, 0, true, true, 4);
    TILE(t + 2, 0, 1, 2, 3, 1, true, true, 4);
    TILE(t + 3, 1, 0, 3, 0, 2, true, true, 4);
  }
  // Tail: tiles 60..63 (60 stages 63; no further staging).
  TILE(NT - 4, 0, 1, 0, 1, 3, true,  true,  4);   // end: 62 landed
  TILE(NT - 3, 1, 0, 1, 2, 0, false, true,  0);   // end: 63 landed
  TILE(NT - 2, 0, 1, 2, 3, 1, false, true,  -1);  // reads tile 63 lo
  TILE(NT - 1, 1, 0, 3, 0, 2, false, false, -1);

  // Epilogue: D = rint(alpha*acc + beta*bias[n]).
  // C/D layout (16x16): col = lane&15, row = (lane>>4)*4 + reg.
  const float alpha = *alpha_p;
  const float beta  = *beta_p;
  const int col0 = bn + wc * 64 + frow;
  float bb4[4];
#pragma unroll
  for (int nj = 0; nj < 4; ++nj) bb4[nj] = beta * (float)bias[col0 + nj * 16];

  const int rbase = bm + wr * 128 + (lane >> 4) * 4;
#pragma unroll
  for (int mi = 0; mi < 8; ++mi) {
#pragma unroll
    for (int r = 0; r < 4; ++r) {
      size_t rowoff = (size_t)(rbase + mi * 16 + r) * N_DIM;
#pragma unroll
      for (int nj = 0; nj < 4; ++nj) {
        out[rowoff + col0 + nj * 16] =
            (int)rintf(fmaf(alpha, (float)acc[mi][nj][r], bb4[nj]));
      }
    }
  }
#undef STAGE_A
#undef STAGE_B
#undef READ_HI
#undef READ_LO
#undef MFMA_LO
#undef MFMA_HI
#undef TILE
}

// ---------------------------------------------------------------------------
// Safety fallback if ws is too small for the packed operands (slow but right).
// ---------------------------------------------------------------------------
__global__ void naive_kernel(const int* __restrict__ x, const int* __restrict__ w,
                             const int* __restrict__ bias,
                             const float* __restrict__ alpha_p,
                             const float* __restrict__ beta_p,
                             int* __restrict__ out) {
  size_t idx = (size_t)blockIdx.x * 256 + threadIdx.x;
  int m = (int)(idx / N_DIM);
  int n = (int)(idx % N_DIM);
  const int4* xr = (const int4*)(x + (size_t)m * K_DIM);
  const int4* wr = (const int4*)(w + (size_t)n * K_DIM);
  int acc = 0;
  for (int k = 0; k < K_DIM / 4; ++k) {
    int4 a = xr[k];
    int4 b = wr[k];
    acc += a.x * b.x + a.y * b.y + a.z * b.z + a.w * b.w;
  }
  out[idx] = (int)rintf(fmaf(*alpha_p, (float)acc, (*beta_p) * (float)bias[n]));
}

extern "C" void kernel_launch(void* const* d_in, const int* in_sizes, int n_in,
                              void* d_out, int out_size, void* d_ws, size_t ws_size,
                              hipStream_t stream) {
  const int*   x     = (const int*)d_in[0];
  const int*   w     = (const int*)d_in[1];
  const int*   bias  = (const int*)d_in[2];
  const float* alpha = (const float*)d_in[3];
  const float* beta  = (const float*)d_in[4];
  int* out = (int*)d_out;

  const size_t a8_bytes = (size_t)M_DIM * K_DIM;  // 32 MiB
  const size_t b8_bytes = (size_t)N_DIM * K_DIM;  // 16 MiB

  if (ws_size >= a8_bytes + b8_bytes) {
    char* A8 = (char*)d_ws;
    char* B8 = A8 + a8_bytes;
    const int nA = (int)(a8_bytes / 16);
    const int nTot = (int)((a8_bytes + b8_bytes) / 16);
    pack_both_kernel<<<2048, 256, 0, stream>>>(x, w, A8, B8, nA, nTot);
    const int nblk = (M_DIM / BM) * (N_DIM / BN);  // 32*16 = 512
    gemm_i8_kernel<<<nblk, 512, 0, stream>>>(A8, B8, bias, alpha, beta, out);
  } else {
    naive_kernel<<<(M_DIM * (size_t)N_DIM) / 256, 256, 0, stream>>>(x, w, bias, alpha, beta, out);
  }
}